// Round 1
// baseline (192.609 us; speedup 1.0000x reference)
//
#include <hip/hip_runtime.h>
#include <hip/hip_bf16.h>

#define SEQ 2048
#define DMODEL 1024
#define NHEAD 16
#define DKH 64

typedef __hip_bfloat16 bf16;
typedef __attribute__((ext_vector_type(8))) short short8;
typedef __attribute__((ext_vector_type(4))) float f32x4;

#define NEG_INF (-__builtin_inff())

__device__ __forceinline__ unsigned short f2bf_bits(float f) {
    bf16 h = __float2bfloat16(f);
    return *reinterpret_cast<unsigned short*>(&h);
}

// ---------------- cast x (fp32 -> bf16), vectorized ----------------
__global__ __launch_bounds__(256) void cast_x_kernel(const float* __restrict__ x,
                                                     bf16* __restrict__ xb) {
    int i = (blockIdx.x * 256 + threadIdx.x) * 4;
    float4 v = *(const float4*)(x + i);
    ushort4 o;
    o.x = f2bf_bits(v.x); o.y = f2bf_bits(v.y);
    o.z = f2bf_bits(v.z); o.w = f2bf_bits(v.w);
    *(ushort4*)(xb + i) = o;
}

// ---------------- transpose + cast W [K][N] fp32 -> Wt [N][K] bf16 ----------------
__global__ __launch_bounds__(256) void transpose_cast_w(const float* __restrict__ W,
                                                        bf16* __restrict__ Wt) {
    __shared__ float tile[32][33];
    int bx = blockIdx.x * 32;  // n base
    int by = blockIdx.y * 32;  // k base
    int tx = threadIdx.x;      // 0..31
    int ty = threadIdx.y;      // 0..7
    for (int i = 0; i < 32; i += 8)
        tile[ty + i][tx] = W[(by + ty + i) * DMODEL + bx + tx];
    __syncthreads();
    for (int i = 0; i < 32; i += 8)
        Wt[(bx + ty + i) * DMODEL + by + tx] = __float2bfloat16(tile[tx][ty + i]);
}

// ---------------- GEMM: C[m][n] = sum_k A[m][k]*Bt[n][k] + bias[n] ----------------
// A: [2048][1024] bf16 row-major.  Bt: [1024][1024] bf16 (transposed weight).
// MODE 0: out bf16 [M][1024]   (Q, K projections)
// MODE 1: out bf16 [1024][2048] transposed (V^T)
// MODE 2: out f32  [M][1024] = acc + bias + resid   (final projection + residual)
template <int MODE>
__global__ __launch_bounds__(256) void gemm_bt(const bf16* __restrict__ A,
                                               const bf16* __restrict__ Bt,
                                               const float* __restrict__ bias,
                                               const float* __restrict__ resid,
                                               void* __restrict__ out) {
    const int m0 = blockIdx.y * 64;
    const int n0 = blockIdx.x * 64;
    __shared__ __align__(16) bf16 As[64 * 72];
    __shared__ __align__(16) bf16 Bs[64 * 72];
    const int tid = threadIdx.x;
    const int lane = tid & 63, wid = tid >> 6;
    const int l16 = lane & 15, lhi = lane >> 4;
    const int wr = wid >> 1, wc = wid & 1;

    f32x4 zero = {0.f, 0.f, 0.f, 0.f};
    f32x4 acc[2][2];
    for (int m = 0; m < 2; ++m)
        for (int n = 0; n < 2; ++n) acc[m][n] = zero;

    for (int kt = 0; kt < DMODEL; kt += 64) {
        __syncthreads();
        for (int i = 0; i < 2; ++i) {
            int idx = tid + i * 256;         // 0..511
            int row = idx >> 3, c8 = (idx & 7) * 8;
            *(uint4*)(&As[row * 72 + c8]) = *(const uint4*)(&A[(m0 + row) * DMODEL + kt + c8]);
            *(uint4*)(&Bs[row * 72 + c8]) = *(const uint4*)(&Bt[(n0 + row) * DMODEL + kt + c8]);
        }
        __syncthreads();
        for (int c = 0; c < 2; ++c) {
            short8 af[2], bfr[2];
            for (int m = 0; m < 2; ++m)
                af[m] = *(const short8*)(&As[(wr * 32 + m * 16 + l16) * 72 + c * 32 + lhi * 8]);
            for (int n = 0; n < 2; ++n)
                bfr[n] = *(const short8*)(&Bs[(wc * 32 + n * 16 + l16) * 72 + c * 32 + lhi * 8]);
            for (int m = 0; m < 2; ++m)
                for (int n = 0; n < 2; ++n)
                    acc[m][n] = __builtin_amdgcn_mfma_f32_16x16x32_bf16(af[m], bfr[n], acc[m][n], 0, 0, 0);
        }
    }

    for (int m = 0; m < 2; ++m)
        for (int n = 0; n < 2; ++n) {
            int gm_base = m0 + wr * 32 + m * 16 + lhi * 4;
            int gn = n0 + wc * 32 + n * 16 + l16;
            float bv = bias[gn];
            for (int r = 0; r < 4; ++r) {
                int gm = gm_base + r;
                float v = acc[m][n][r] + bv;
                if (MODE == 0) {
                    ((bf16*)out)[gm * DMODEL + gn] = __float2bfloat16(v);
                } else if (MODE == 1) {
                    ((bf16*)out)[gn * SEQ + gm] = __float2bfloat16(v);
                } else {
                    ((float*)out)[gm * DMODEL + gn] = v + resid[gm * DMODEL + gn];
                }
            }
        }
}

// ---------------- flash-style causal attention ----------------
// Q, K: bf16 [SEQ][DMODEL] (head h in cols h*64..h*64+63).  Vt: bf16 [DMODEL][SEQ].
// ctx out: bf16 [SEQ][DMODEL].
__global__ __launch_bounds__(256) void attn_kernel(const bf16* __restrict__ Q,
                                                   const bf16* __restrict__ K,
                                                   const bf16* __restrict__ Vt,
                                                   bf16* __restrict__ ctx) {
    const int qb = blockIdx.x;   // query block of 64
    const int h = blockIdx.y;
    const int tid = threadIdx.x;
    const int lane = tid & 63, wid = tid >> 6;
    const int l16 = lane & 15, lhi = lane >> 4;

    __shared__ __align__(16) bf16 Ks[64 * 72];
    __shared__ __align__(16) bf16 Vs[64 * 72];
    __shared__ __align__(16) bf16 Ps[4][16 * 72];

    const int q0w = qb * 64 + wid * 16;  // this wave's first query row

    // preload Q fragments (rows = l16, k-chunks c*32 + lhi*8)
    short8 qf[2];
    for (int c = 0; c < 2; ++c)
        qf[c] = *(const short8*)(&Q[(q0w + l16) * DMODEL + h * DKH + c * 32 + lhi * 8]);

    f32x4 zero = {0.f, 0.f, 0.f, 0.f};
    f32x4 oacc[4];
    for (int d = 0; d < 4; ++d) oacc[d] = zero;
    float mrow[4], lrow[4];
    for (int r = 0; r < 4; ++r) { mrow[r] = NEG_INF; lrow[r] = 0.f; }

    for (int kt = 0; kt <= qb; ++kt) {
        __syncthreads();
        // stage K tile [64 keys][64 dk] and V^T tile [64 d][64 keys]
        for (int i = 0; i < 2; ++i) {
            int idx = tid + i * 256;
            int row = idx >> 3, c8 = (idx & 7) * 8;
            *(uint4*)(&Ks[row * 72 + c8]) = *(const uint4*)(&K[(kt * 64 + row) * DMODEL + h * DKH + c8]);
            *(uint4*)(&Vs[row * 72 + c8]) = *(const uint4*)(&Vt[(h * DKH + row) * SEQ + kt * 64 + c8]);
        }
        __syncthreads();

        // S = Q K^T  (16 q x 64 keys per wave)
        f32x4 s[4];
        for (int n = 0; n < 4; ++n) {
            s[n] = zero;
            for (int c = 0; c < 2; ++c) {
                short8 kf = *(const short8*)(&Ks[(n * 16 + l16) * 72 + c * 32 + lhi * 8]);
                s[n] = __builtin_amdgcn_mfma_f32_16x16x32_bf16(qf[c], kf, s[n], 0, 0, 0);
            }
        }

        // mask (diagonal tile) + scale by 1/8
        const bool diag = (kt == qb);
        for (int n = 0; n < 4; ++n)
            for (int r = 0; r < 4; ++r) {
                float v = s[n][r] * 0.125f;
                if (diag && (kt * 64 + n * 16 + l16) > (q0w + lhi * 4 + r)) v = NEG_INF;
                s[n][r] = v;
            }

        // row max across n-tiles and the 16 lanes of the group
        float rm[4];
        for (int r = 0; r < 4; ++r)
            rm[r] = fmaxf(fmaxf(s[0][r], s[1][r]), fmaxf(s[2][r], s[3][r]));
        for (int off = 1; off < 16; off <<= 1)
            for (int r = 0; r < 4; ++r) rm[r] = fmaxf(rm[r], __shfl_xor(rm[r], off, 64));

        float alpha[4];
        for (int r = 0; r < 4; ++r) {
            float mnew = fmaxf(mrow[r], rm[r]);
            alpha[r] = __expf(mrow[r] - mnew);
            mrow[r] = mnew;
        }

        // P = exp(S - m), row sums
        float rs[4] = {0.f, 0.f, 0.f, 0.f};
        for (int n = 0; n < 4; ++n)
            for (int r = 0; r < 4; ++r) {
                float p = __expf(s[n][r] - mrow[r]);
                s[n][r] = p;
                rs[r] += p;
            }
        for (int off = 1; off < 16; off <<= 1)
            for (int r = 0; r < 4; ++r) rs[r] += __shfl_xor(rs[r], off, 64);
        for (int r = 0; r < 4; ++r) lrow[r] = lrow[r] * alpha[r] + rs[r];

        // rescale O accumulator
        for (int d = 0; d < 4; ++d)
            for (int r = 0; r < 4; ++r) oacc[d][r] *= alpha[r];

        // write P (bf16) into per-wave LDS region in [16 q][64 k] layout
        for (int n = 0; n < 4; ++n)
            for (int r = 0; r < 4; ++r)
                Ps[wid][(lhi * 4 + r) * 72 + n * 16 + l16] = __float2bfloat16(s[n][r]);
        __syncthreads();

        // O += P @ V
        short8 pa[2];
        for (int c = 0; c < 2; ++c)
            pa[c] = *(const short8*)(&Ps[wid][l16 * 72 + c * 32 + lhi * 8]);
        for (int dn = 0; dn < 4; ++dn)
            for (int c = 0; c < 2; ++c) {
                short8 vb = *(const short8*)(&Vs[(dn * 16 + l16) * 72 + c * 32 + lhi * 8]);
                oacc[dn] = __builtin_amdgcn_mfma_f32_16x16x32_bf16(pa[c], vb, oacc[dn], 0, 0, 0);
            }
        __syncthreads();
    }

    // epilogue: ctx = O / l
    for (int dn = 0; dn < 4; ++dn)
        for (int r = 0; r < 4; ++r) {
            int gq = q0w + lhi * 4 + r;
            int gd = h * DKH + dn * 16 + l16;
            ctx[gq * DMODEL + gd] = __float2bfloat16(oacc[dn][r] / lrow[r]);
        }
}

// ---------------- row LayerNorm ----------------
__global__ __launch_bounds__(256) void ln_kernel(const float* __restrict__ y,
                                                 const float* __restrict__ gamma,
                                                 const float* __restrict__ beta,
                                                 float* __restrict__ out) {
    const int row = blockIdx.x;
    const int col = threadIdx.x * 4;
    float4 v = *(const float4*)(y + row * DMODEL + col);
    float s = v.x + v.y + v.z + v.w;
    float q = v.x * v.x + v.y * v.y + v.z * v.z + v.w * v.w;
    for (int off = 1; off < 64; off <<= 1) {
        s += __shfl_xor(s, off, 64);
        q += __shfl_xor(q, off, 64);
    }
    __shared__ float ss[4], sq[4];
    int wid = threadIdx.x >> 6;
    if ((threadIdx.x & 63) == 0) { ss[wid] = s; sq[wid] = q; }
    __syncthreads();
    s = ss[0] + ss[1] + ss[2] + ss[3];
    q = sq[0] + sq[1] + sq[2] + sq[3];
    float mu = s * (1.f / DMODEL);
    float var = q * (1.f / DMODEL) - mu * mu;
    float rstd = rsqrtf(var + 1e-5f);
    float4 g = *(const float4*)(gamma + col);
    float4 b = *(const float4*)(beta + col);
    float4 o;
    o.x = (v.x - mu) * rstd * g.x + b.x;
    o.y = (v.y - mu) * rstd * g.y + b.y;
    o.z = (v.z - mu) * rstd * g.z + b.z;
    o.w = (v.w - mu) * rstd * g.w + b.w;
    *(float4*)(out + row * DMODEL + col) = o;
}

extern "C" void kernel_launch(void* const* d_in, const int* in_sizes, int n_in,
                              void* d_out, int out_size, void* d_ws, size_t ws_size,
                              hipStream_t stream) {
    const float* x     = (const float*)d_in[0];
    const float* Wq    = (const float*)d_in[1];
    const float* bq    = (const float*)d_in[2];
    const float* Wk    = (const float*)d_in[3];
    const float* bk    = (const float*)d_in[4];
    const float* Wv    = (const float*)d_in[5];
    const float* bv    = (const float*)d_in[6];
    const float* Wo    = (const float*)d_in[7];
    const float* bo    = (const float*)d_in[8];
    const float* gamma = (const float*)d_in[9];
    const float* beta  = (const float*)d_in[10];
    float* out = (float*)d_out;

    char* w = (char*)d_ws;
    bf16* xb   = (bf16*)w;  w += (size_t)SEQ * DMODEL * 2;      // 4 MiB
    bf16* Wqt  = (bf16*)w;  w += (size_t)DMODEL * DMODEL * 2;   // 2 MiB
    bf16* Wkt  = (bf16*)w;  w += (size_t)DMODEL * DMODEL * 2;
    bf16* Wvt  = (bf16*)w;  w += (size_t)DMODEL * DMODEL * 2;
    bf16* Wot  = (bf16*)w;  w += (size_t)DMODEL * DMODEL * 2;
    bf16* Qb   = (bf16*)w;  w += (size_t)SEQ * DMODEL * 2;
    bf16* Kb   = (bf16*)w;  w += (size_t)SEQ * DMODEL * 2;
    bf16* Vtb  = (bf16*)w;  w += (size_t)DMODEL * SEQ * 2;      // [D][SEQ]
    bf16* ctxb = (bf16*)w;  w += (size_t)SEQ * DMODEL * 2;
    float* yb  = (float*)w; w += (size_t)SEQ * DMODEL * 4;      // 8 MiB

    // 1. cast x to bf16
    cast_x_kernel<<<SEQ * DMODEL / (256 * 4), 256, 0, stream>>>(x, xb);

    // 2. transpose+cast weights
    dim3 tgrid(DMODEL / 32, DMODEL / 32), tblk(32, 8);
    transpose_cast_w<<<tgrid, tblk, 0, stream>>>(Wq, Wqt);
    transpose_cast_w<<<tgrid, tblk, 0, stream>>>(Wk, Wkt);
    transpose_cast_w<<<tgrid, tblk, 0, stream>>>(Wv, Wvt);
    transpose_cast_w<<<tgrid, tblk, 0, stream>>>(Wo, Wot);

    // 3. projections
    dim3 ggrid(DMODEL / 64, SEQ / 64);
    gemm_bt<0><<<ggrid, 256, 0, stream>>>(xb, Wqt, bq, nullptr, (void*)Qb);
    gemm_bt<0><<<ggrid, 256, 0, stream>>>(xb, Wkt, bk, nullptr, (void*)Kb);
    gemm_bt<1><<<ggrid, 256, 0, stream>>>(xb, Wvt, bv, nullptr, (void*)Vtb);

    // 4. attention
    dim3 agrid(SEQ / 64, NHEAD);
    attn_kernel<<<agrid, 256, 0, stream>>>(Qb, Kb, Vtb, ctxb);

    // 5. output projection + residual
    gemm_bt<2><<<ggrid, 256, 0, stream>>>(ctxb, Wot, bo, x, (void*)yb);

    // 6. LayerNorm
    ln_kernel<<<SEQ, 256, 0, stream>>>(yb, gamma, beta, out);
}

// Round 2
// 184.454 us; speedup vs baseline: 1.0442x; 1.0442x over previous
//
#include <hip/hip_runtime.h>
#include <hip/hip_bf16.h>

#define SEQ 2048
#define DMODEL 1024
#define NHEAD 16
#define DKH 64

typedef __hip_bfloat16 bf16;
typedef __attribute__((ext_vector_type(8))) short short8;
typedef __attribute__((ext_vector_type(4))) float f32x4;

__device__ __forceinline__ unsigned short f2bf_bits(float f) {
    bf16 h = __float2bfloat16(f);
    return *reinterpret_cast<unsigned short*>(&h);
}

__device__ __forceinline__ unsigned pack_bf2(float a, float b) {
    return (unsigned)f2bf_bits(a) | ((unsigned)f2bf_bits(b) << 16);
}

// ---------------- cast x (fp32 -> bf16), vectorized ----------------
__global__ __launch_bounds__(256) void cast_x_kernel(const float* __restrict__ x,
                                                     bf16* __restrict__ xb) {
    int i = (blockIdx.x * 256 + threadIdx.x) * 4;
    float4 v = *(const float4*)(x + i);
    ushort4 o;
    o.x = f2bf_bits(v.x); o.y = f2bf_bits(v.y);
    o.z = f2bf_bits(v.z); o.w = f2bf_bits(v.w);
    *(ushort4*)(xb + i) = o;
}

// ---------------- transpose + cast W [K][N] fp32 -> Wt [N][K] bf16 ----------------
__global__ __launch_bounds__(256) void transpose_cast_w(const float* __restrict__ W,
                                                        bf16* __restrict__ Wt) {
    __shared__ float tile[32][33];
    int bx = blockIdx.x * 32;  // n base
    int by = blockIdx.y * 32;  // k base
    int tx = threadIdx.x;      // 0..31
    int ty = threadIdx.y;      // 0..7
    for (int i = 0; i < 32; i += 8)
        tile[ty + i][tx] = W[(by + ty + i) * DMODEL + bx + tx];
    __syncthreads();
    for (int i = 0; i < 32; i += 8)
        Wt[(bx + ty + i) * DMODEL + by + tx] = __float2bfloat16(tile[tx][ty + i]);
}

// ---------------- GEMM: C[m][n] = (sum_k A[m][k]*Bt[n][k] + bias[n]) * scale ----------------
// MODE 0: out bf16 [M][1024]   (Q, K projections; Q uses scale=0.125)
// MODE 1: out bf16 [1024][2048] transposed (V^T)
// MODE 2: out f32  [M][1024] = acc + bias + resid   (final projection + residual)
template <int MODE>
__global__ __launch_bounds__(256) void gemm_bt(const bf16* __restrict__ A,
                                               const bf16* __restrict__ Bt,
                                               const float* __restrict__ bias,
                                               const float* __restrict__ resid,
                                               void* __restrict__ out, float scale) {
    const int m0 = blockIdx.y * 64;
    const int n0 = blockIdx.x * 64;
    __shared__ __align__(16) bf16 As[64 * 72];
    __shared__ __align__(16) bf16 Bs[64 * 72];
    const int tid = threadIdx.x;
    const int lane = tid & 63, wid = tid >> 6;
    const int l16 = lane & 15, lhi = lane >> 4;
    const int wr = wid >> 1, wc = wid & 1;

    f32x4 zero = {0.f, 0.f, 0.f, 0.f};
    f32x4 acc[2][2];
    for (int m = 0; m < 2; ++m)
        for (int n = 0; n < 2; ++n) acc[m][n] = zero;

    for (int kt = 0; kt < DMODEL; kt += 64) {
        __syncthreads();
        for (int i = 0; i < 2; ++i) {
            int idx = tid + i * 256;         // 0..511
            int row = idx >> 3, c8 = (idx & 7) * 8;
            *(uint4*)(&As[row * 72 + c8]) = *(const uint4*)(&A[(m0 + row) * DMODEL + kt + c8]);
            *(uint4*)(&Bs[row * 72 + c8]) = *(const uint4*)(&Bt[(n0 + row) * DMODEL + kt + c8]);
        }
        __syncthreads();
        for (int c = 0; c < 2; ++c) {
            short8 af[2], bfr[2];
            for (int m = 0; m < 2; ++m)
                af[m] = *(const short8*)(&As[(wr * 32 + m * 16 + l16) * 72 + c * 32 + lhi * 8]);
            for (int n = 0; n < 2; ++n)
                bfr[n] = *(const short8*)(&Bs[(wc * 32 + n * 16 + l16) * 72 + c * 32 + lhi * 8]);
            for (int m = 0; m < 2; ++m)
                for (int n = 0; n < 2; ++n)
                    acc[m][n] = __builtin_amdgcn_mfma_f32_16x16x32_bf16(af[m], bfr[n], acc[m][n], 0, 0, 0);
        }
    }

    for (int m = 0; m < 2; ++m)
        for (int n = 0; n < 2; ++n) {
            int gm_base = m0 + wr * 32 + m * 16 + lhi * 4;
            int gn = n0 + wc * 32 + n * 16 + l16;
            float bv = bias[gn];
            for (int r = 0; r < 4; ++r) {
                int gm = gm_base + r;
                float v = (acc[m][n][r] + bv) * scale;
                if (MODE == 0) {
                    ((bf16*)out)[gm * DMODEL + gn] = __float2bfloat16(v);
                } else if (MODE == 1) {
                    ((bf16*)out)[gn * SEQ + gm] = __float2bfloat16(v);
                } else {
                    ((float*)out)[gm * DMODEL + gn] = v + resid[gm * DMODEL + gn];
                }
            }
        }
}

// ---------------- barrier-free swapped-operand flash attention ----------------
// One wave (64 threads) per block; wave handles 32 queries (two 16-row groups).
// Q,K: bf16 [SEQ][DMODEL] (head h at cols h*64..); Vt: bf16 [DMODEL][SEQ].
// Q is pre-scaled by 1/8 at projection. No LDS, no __syncthreads.
//
// Swapped QK^T: S^T = K·Q^T via mfma(A=K-frag, B=Q-frag):
//   lane (l16, m=lane>>4) holds S^T[key = n*16 + m*4 + r][query = l16].
// PV: O^T = V^T·P^T via mfma(A=Vt-frag, B=P^T-frag); P^T B-frag assembled
// in-register by 4-lane-column shuffles of packed bf16 pairs.
__global__ __launch_bounds__(64) void attn_kernel(const bf16* __restrict__ Q,
                                                  const bf16* __restrict__ K,
                                                  const bf16* __restrict__ Vt,
                                                  bf16* __restrict__ ctx) {
    // load-balance remap: pair short (low qt) with long (high qt) blocks
    int bx = blockIdx.x;
    const int qt = (bx & 1) ? (63 - (bx >> 1)) : (bx >> 1);   // 0..63
    const int h = blockIdx.y;
    const int lane = threadIdx.x;
    const int l16 = lane & 15, m = lane >> 4;
    const int q0 = qt * 32;

    // Q fragments (B-operand): lane provides Q[q0+g*16+l16][d = c*32 + m*8 + j]
    short8 qf[2][2];
    for (int g = 0; g < 2; ++g)
        for (int c = 0; c < 2; ++c)
            qf[g][c] = *(const short8*)(&Q[(q0 + g * 16 + l16) * DMODEL + h * DKH + c * 32 + m * 8]);

    f32x4 zero = {0.f, 0.f, 0.f, 0.f};
    f32x4 oacc[2][4];
    for (int g = 0; g < 2; ++g)
        for (int dn = 0; dn < 4; ++dn) oacc[g][dn] = zero;
    float mr[2] = {-1e30f, -1e30f};
    float lr[2] = {0.f, 0.f};

    const int nt = (qt >> 1) + 1;
    const int srcA = l16 + ((m & 1) << 5);   // lane l16 + 16*((m&1)*2)
    const int srcB = srcA + 16;
    const bool hi = (m >> 1) != 0;

    for (int t = 0; t < nt; ++t) {
        const int k0 = t * 64;

        // K fragments (A-operand): K[k0 + n*16 + l16][c*32 + m*8 + j]
        short8 kf[4][2];
        for (int n = 0; n < 4; ++n)
            for (int c = 0; c < 2; ++c)
                kf[n][c] = *(const short8*)(&K[(k0 + n * 16 + l16) * DMODEL + h * DKH + c * 32 + m * 8]);

        // S^T = K Q^T for both query groups
        f32x4 s[2][4];
        for (int g = 0; g < 2; ++g)
            for (int n = 0; n < 4; ++n) {
                f32x4 a = zero;
                a = __builtin_amdgcn_mfma_f32_16x16x32_bf16(kf[n][0], qf[g][0], a, 0, 0, 0);
                a = __builtin_amdgcn_mfma_f32_16x16x32_bf16(kf[n][1], qf[g][1], a, 0, 0, 0);
                s[g][n] = a;
            }

        const bool masked = (t == nt - 1);
        unsigned pk01[2][4], pk23[2][4];

        for (int g = 0; g < 2; ++g) {
            const int q = q0 + g * 16 + l16;
            float tm = -1e30f;
            for (int n = 0; n < 4; ++n)
                for (int r = 0; r < 4; ++r) {
                    float v = s[g][n][r];
                    if (masked && (k0 + n * 16 + m * 4 + r) > q) v = -1e30f;
                    s[g][n][r] = v;
                    tm = fmaxf(tm, v);
                }
            tm = fmaxf(tm, __shfl_xor(tm, 16, 64));
            tm = fmaxf(tm, __shfl_xor(tm, 32, 64));
            float mnew = fmaxf(mr[g], tm);
            float alpha = __expf(mr[g] - mnew);
            mr[g] = mnew;
            float rs = 0.f;
            for (int n = 0; n < 4; ++n) {
                float p0 = __expf(s[g][n][0] - mnew);
                float p1 = __expf(s[g][n][1] - mnew);
                float p2 = __expf(s[g][n][2] - mnew);
                float p3 = __expf(s[g][n][3] - mnew);
                rs += (p0 + p1) + (p2 + p3);
                pk01[g][n] = pack_bf2(p0, p1);
                pk23[g][n] = pack_bf2(p2, p3);
            }
            rs += __shfl_xor(rs, 16, 64);
            rs += __shfl_xor(rs, 32, 64);
            lr[g] = lr[g] * alpha + rs;
            for (int dn = 0; dn < 4; ++dn)
                for (int r = 0; r < 4; ++r) oacc[g][dn][r] *= alpha;
        }

        // V^T fragments (A-operand): Vt[h*64 + dn*16 + l16][k0 + c*32 + m*8 + j]
        short8 vf[4][2];
        for (int dn = 0; dn < 4; ++dn)
            for (int c = 0; c < 2; ++c)
                vf[dn][c] = *(const short8*)(&Vt[(h * DKH + dn * 16 + l16) * SEQ + k0 + c * 32 + m * 8]);

        // assemble P^T B-frags by shuffle and do PV
        for (int g = 0; g < 2; ++g) {
            union { short8 s8; unsigned u[4]; } bfr[2];
            for (int cb = 0; cb < 2; ++cb) {
                unsigned w0a = __shfl((int)pk01[g][2 * cb], srcA, 64);
                unsigned w0b = __shfl((int)pk01[g][2 * cb + 1], srcA, 64);
                unsigned w1a = __shfl((int)pk23[g][2 * cb], srcA, 64);
                unsigned w1b = __shfl((int)pk23[g][2 * cb + 1], srcA, 64);
                unsigned w2a = __shfl((int)pk01[g][2 * cb], srcB, 64);
                unsigned w2b = __shfl((int)pk01[g][2 * cb + 1], srcB, 64);
                unsigned w3a = __shfl((int)pk23[g][2 * cb], srcB, 64);
                unsigned w3b = __shfl((int)pk23[g][2 * cb + 1], srcB, 64);
                bfr[cb].u[0] = hi ? w0b : w0a;
                bfr[cb].u[1] = hi ? w1b : w1a;
                bfr[cb].u[2] = hi ? w2b : w2a;
                bfr[cb].u[3] = hi ? w3b : w3a;
            }
            for (int dn = 0; dn < 4; ++dn) {
                oacc[g][dn] = __builtin_amdgcn_mfma_f32_16x16x32_bf16(vf[dn][0], bfr[0].s8, oacc[g][dn], 0, 0, 0);
                oacc[g][dn] = __builtin_amdgcn_mfma_f32_16x16x32_bf16(vf[dn][1], bfr[1].s8, oacc[g][dn], 0, 0, 0);
            }
        }
    }

    // epilogue: ctx[q][h*64 + d] = O^T[d][q] / l[q]
    for (int g = 0; g < 2; ++g) {
        float inv = 1.f / lr[g];
        bf16* base = ctx + (size_t)(q0 + g * 16 + l16) * DMODEL + h * DKH + m * 4;
        for (int dn = 0; dn < 4; ++dn) {
            unsigned a = pack_bf2(oacc[g][dn][0] * inv, oacc[g][dn][1] * inv);
            unsigned b = pack_bf2(oacc[g][dn][2] * inv, oacc[g][dn][3] * inv);
            *(unsigned*)(base + dn * 16) = a;
            *(unsigned*)(base + dn * 16 + 2) = b;
        }
    }
}

// ---------------- row LayerNorm ----------------
__global__ __launch_bounds__(256) void ln_kernel(const float* __restrict__ y,
                                                 const float* __restrict__ gamma,
                                                 const float* __restrict__ beta,
                                                 float* __restrict__ out) {
    const int row = blockIdx.x;
    const int col = threadIdx.x * 4;
    float4 v = *(const float4*)(y + row * DMODEL + col);
    float s = v.x + v.y + v.z + v.w;
    float q = v.x * v.x + v.y * v.y + v.z * v.z + v.w * v.w;
    for (int off = 1; off < 64; off <<= 1) {
        s += __shfl_xor(s, off, 64);
        q += __shfl_xor(q, off, 64);
    }
    __shared__ float ss[4], sq[4];
    int wid = threadIdx.x >> 6;
    if ((threadIdx.x & 63) == 0) { ss[wid] = s; sq[wid] = q; }
    __syncthreads();
    s = ss[0] + ss[1] + ss[2] + ss[3];
    q = sq[0] + sq[1] + sq[2] + sq[3];
    float mu = s * (1.f / DMODEL);
    float var = q * (1.f / DMODEL) - mu * mu;
    float rstd = rsqrtf(var + 1e-5f);
    float4 g = *(const float4*)(gamma + col);
    float4 b = *(const float4*)(beta + col);
    float4 o;
    o.x = (v.x - mu) * rstd * g.x + b.x;
    o.y = (v.y - mu) * rstd * g.y + b.y;
    o.z = (v.z - mu) * rstd * g.z + b.z;
    o.w = (v.w - mu) * rstd * g.w + b.w;
    *(float4*)(out + row * DMODEL + col) = o;
}

extern "C" void kernel_launch(void* const* d_in, const int* in_sizes, int n_in,
                              void* d_out, int out_size, void* d_ws, size_t ws_size,
                              hipStream_t stream) {
    const float* x     = (const float*)d_in[0];
    const float* Wq    = (const float*)d_in[1];
    const float* bq    = (const float*)d_in[2];
    const float* Wk    = (const float*)d_in[3];
    const float* bk    = (const float*)d_in[4];
    const float* Wv    = (const float*)d_in[5];
    const float* bv    = (const float*)d_in[6];
    const float* Wo    = (const float*)d_in[7];
    const float* bo    = (const float*)d_in[8];
    const float* gamma = (const float*)d_in[9];
    const float* beta  = (const float*)d_in[10];
    float* out = (float*)d_out;

    char* w = (char*)d_ws;
    bf16* xb   = (bf16*)w;  w += (size_t)SEQ * DMODEL * 2;
    bf16* Wqt  = (bf16*)w;  w += (size_t)DMODEL * DMODEL * 2;
    bf16* Wkt  = (bf16*)w;  w += (size_t)DMODEL * DMODEL * 2;
    bf16* Wvt  = (bf16*)w;  w += (size_t)DMODEL * DMODEL * 2;
    bf16* Wot  = (bf16*)w;  w += (size_t)DMODEL * DMODEL * 2;
    bf16* Qb   = (bf16*)w;  w += (size_t)SEQ * DMODEL * 2;
    bf16* Kb   = (bf16*)w;  w += (size_t)SEQ * DMODEL * 2;
    bf16* Vtb  = (bf16*)w;  w += (size_t)DMODEL * SEQ * 2;
    bf16* ctxb = (bf16*)w;  w += (size_t)SEQ * DMODEL * 2;
    float* yb  = (float*)w; w += (size_t)SEQ * DMODEL * 4;

    // 1. cast x to bf16
    cast_x_kernel<<<SEQ * DMODEL / (256 * 4), 256, 0, stream>>>(x, xb);

    // 2. transpose+cast weights
    dim3 tgrid(DMODEL / 32, DMODEL / 32), tblk(32, 8);
    transpose_cast_w<<<tgrid, tblk, 0, stream>>>(Wq, Wqt);
    transpose_cast_w<<<tgrid, tblk, 0, stream>>>(Wk, Wkt);
    transpose_cast_w<<<tgrid, tblk, 0, stream>>>(Wv, Wvt);
    transpose_cast_w<<<tgrid, tblk, 0, stream>>>(Wo, Wot);

    // 3. projections (Q pre-scaled by 1/sqrt(DK) = 1/8)
    dim3 ggrid(DMODEL / 64, SEQ / 64);
    gemm_bt<0><<<ggrid, 256, 0, stream>>>(xb, Wqt, bq, nullptr, (void*)Qb, 0.125f);
    gemm_bt<0><<<ggrid, 256, 0, stream>>>(xb, Wkt, bk, nullptr, (void*)Kb, 1.0f);
    gemm_bt<1><<<ggrid, 256, 0, stream>>>(xb, Wvt, bv, nullptr, (void*)Vtb, 1.0f);

    // 4. attention: one wave per 32-query tile per head
    dim3 agrid(SEQ / 32, NHEAD);
    attn_kernel<<<agrid, 64, 0, stream>>>(Qb, Kb, Vtb, ctxb);

    // 5. output projection + residual
    gemm_bt<2><<<ggrid, 256, 0, stream>>>(ctxb, Wot, bo, x, (void*)yb, 1.0f);

    // 6. LayerNorm
    ln_kernel<<<SEQ, 256, 0, stream>>>(yb, gamma, beta, out);
}

// Round 3
// 134.209 us; speedup vs baseline: 1.4351x; 1.3744x over previous
//
#include <hip/hip_runtime.h>
#include <hip/hip_bf16.h>

#define SEQ 2048
#define DMODEL 1024
#define NHEAD 16
#define DKH 64
#define NSPLIT 2

typedef __hip_bfloat16 bf16;
typedef __attribute__((ext_vector_type(8))) short short8;
typedef __attribute__((ext_vector_type(4))) float f32x4;

__device__ __forceinline__ unsigned short f2bf_bits(float f) {
    bf16 h = __float2bfloat16(f);
    return *reinterpret_cast<unsigned short*>(&h);
}

__device__ __forceinline__ unsigned pack_bf2(float a, float b) {
    return (unsigned)f2bf_bits(a) | ((unsigned)f2bf_bits(b) << 16);
}

// ---------------- cast x (fp32 -> bf16) ----------------
__global__ __launch_bounds__(256) void cast_x_kernel(const float* __restrict__ x,
                                                     bf16* __restrict__ xb) {
    int i = (blockIdx.x * 256 + threadIdx.x) * 4;
    float4 v = *(const float4*)(x + i);
    ushort4 o;
    o.x = f2bf_bits(v.x); o.y = f2bf_bits(v.y);
    o.z = f2bf_bits(v.z); o.w = f2bf_bits(v.w);
    *(ushort4*)(xb + i) = o;
}

// ---------------- batched transpose+cast: 4 weights in one launch ----------------
__global__ __launch_bounds__(256) void transpose_cast_w4(const float* __restrict__ W0,
                                                         const float* __restrict__ W1,
                                                         const float* __restrict__ W2,
                                                         const float* __restrict__ W3,
                                                         bf16* __restrict__ Wt) {
    const float* W = (blockIdx.z == 0) ? W0 : (blockIdx.z == 1) ? W1 : (blockIdx.z == 2) ? W2 : W3;
    bf16* out = Wt + (size_t)blockIdx.z * DMODEL * DMODEL;
    __shared__ float tile[32][33];
    int bx = blockIdx.x * 32;
    int by = blockIdx.y * 32;
    int tx = threadIdx.x;
    int ty = threadIdx.y;
    for (int i = 0; i < 32; i += 8)
        tile[ty + i][tx] = W[(by + ty + i) * DMODEL + bx + tx];
    __syncthreads();
    for (int i = 0; i < 32; i += 8)
        out[(bx + ty + i) * DMODEL + by + tx] = __float2bfloat16(tile[tx][ty + i]);
}

// ---------------- 128x128 GEMM, BK=64, global_load_lds staging (m97 structure) ----------------
// A [M][1024] bf16. Bt [N][1024] bf16 (row n = output col n, K-contiguous).
// FUSED=1: N=3072; n in [0,1024) -> Qb (scaled 1/8), [1024,2048) -> Kb, [2048,3072) -> Vtb transposed.
// FUSED=0: N=1024; yout f32 = acc + bias + resid.
template <int FUSED>
__global__ __launch_bounds__(256) void gemm128(const bf16* __restrict__ A,
                                               const bf16* __restrict__ Bt,
                                               const float* __restrict__ b0,
                                               const float* __restrict__ b1,
                                               const float* __restrict__ b2,
                                               bf16* __restrict__ Qb,
                                               bf16* __restrict__ Kb,
                                               bf16* __restrict__ Vtb,
                                               const float* __restrict__ resid,
                                               float* __restrict__ yout) {
    const int m0 = blockIdx.y * 128;
    const int n0 = blockIdx.x * 128;
    __shared__ __align__(16) bf16 As[128 * 64];
    __shared__ __align__(16) bf16 Bs[128 * 64];
    const int tid = threadIdx.x, lane = tid & 63, wid = tid >> 6;
    const int l16 = lane & 15, lhi = lane >> 4;
    const int wr = wid >> 1, wc = wid & 1;

    f32x4 acc[4][4];
    for (int i = 0; i < 4; ++i)
        for (int j = 0; j < 4; ++j) acc[i][j] = (f32x4){0.f, 0.f, 0.f, 0.f};

    for (int kt = 0; kt < DMODEL; kt += 64) {
        __syncthreads();
        #pragma unroll
        for (int j = 0; j < 4; ++j) {
            const int cb = (j * 4 + wid) * 64;        // chunk base for this call
            const int chunk = cb + lane;
            const int row = chunk >> 3, c16 = chunk & 7;
            const bf16* gA = A + (size_t)(m0 + row) * DMODEL + kt + c16 * 8;
            const bf16* gB = Bt + (size_t)(n0 + row) * DMODEL + kt + c16 * 8;
            __builtin_amdgcn_global_load_lds((const __attribute__((address_space(1))) void*)gA,
                                             (__attribute__((address_space(3))) void*)(As + cb * 8),
                                             16, 0, 0);
            __builtin_amdgcn_global_load_lds((const __attribute__((address_space(1))) void*)gB,
                                             (__attribute__((address_space(3))) void*)(Bs + cb * 8),
                                             16, 0, 0);
        }
        __syncthreads();
        #pragma unroll
        for (int c = 0; c < 2; ++c) {
            short8 af[4], bfm[4];
            #pragma unroll
            for (int mi = 0; mi < 4; ++mi)
                af[mi] = *(const short8*)(&As[(wr * 64 + mi * 16 + l16) * 64 + c * 32 + lhi * 8]);
            #pragma unroll
            for (int ni = 0; ni < 4; ++ni)
                bfm[ni] = *(const short8*)(&Bs[(wc * 64 + ni * 16 + l16) * 64 + c * 32 + lhi * 8]);
            #pragma unroll
            for (int mi = 0; mi < 4; ++mi)
                #pragma unroll
                for (int ni = 0; ni < 4; ++ni)
                    acc[mi][ni] = __builtin_amdgcn_mfma_f32_16x16x32_bf16(af[mi], bfm[ni], acc[mi][ni], 0, 0, 0);
        }
    }

    if (FUSED) {
        const int reg = n0 >> 10;                    // 0=Q 1=K 2=V
        const float* bias = (reg == 0) ? b0 : (reg == 1) ? b1 : b2;
        const int nb = n0 & 1023;
        #pragma unroll
        for (int mi = 0; mi < 4; ++mi)
            #pragma unroll
            for (int ni = 0; ni < 4; ++ni) {
                const int gm = m0 + wr * 64 + mi * 16 + lhi * 4;
                const int gn = nb + wc * 64 + ni * 16 + l16;
                const float bv = bias[gn];
                if (reg == 0) {
                    for (int r = 0; r < 4; ++r)
                        Qb[(size_t)(gm + r) * DMODEL + gn] = __float2bfloat16((acc[mi][ni][r] + bv) * 0.125f);
                } else if (reg == 1) {
                    for (int r = 0; r < 4; ++r)
                        Kb[(size_t)(gm + r) * DMODEL + gn] = __float2bfloat16(acc[mi][ni][r] + bv);
                } else {
                    ushort4 p;
                    p.x = f2bf_bits(acc[mi][ni][0] + bv);
                    p.y = f2bf_bits(acc[mi][ni][1] + bv);
                    p.z = f2bf_bits(acc[mi][ni][2] + bv);
                    p.w = f2bf_bits(acc[mi][ni][3] + bv);
                    *(ushort4*)(&Vtb[(size_t)gn * SEQ + gm]) = p;
                }
            }
    } else {
        #pragma unroll
        for (int mi = 0; mi < 4; ++mi)
            #pragma unroll
            for (int ni = 0; ni < 4; ++ni) {
                const int gm = m0 + wr * 64 + mi * 16 + lhi * 4;
                const int gn = n0 + wc * 64 + ni * 16 + l16;
                const float bv = b0[gn];
                for (int r = 0; r < 4; ++r)
                    yout[(size_t)(gm + r) * DMODEL + gn] =
                        acc[mi][ni][r] + bv + resid[(size_t)(gm + r) * DMODEL + gn];
            }
    }
}

// ---------------- attention: swapped-operand flash, key-split, reg double-buffer ----------------
__device__ __forceinline__ void load_kv(int k0, int h, int l16, int m,
                                        const bf16* __restrict__ K, const bf16* __restrict__ Vt,
                                        short8 (&kf)[4][2], short8 (&vf)[4][2]) {
    #pragma unroll
    for (int n = 0; n < 4; ++n)
        #pragma unroll
        for (int c = 0; c < 2; ++c)
            kf[n][c] = *(const short8*)(&K[(size_t)(k0 + n * 16 + l16) * DMODEL + h * DKH + c * 32 + m * 8]);
    #pragma unroll
    for (int dn = 0; dn < 4; ++dn)
        #pragma unroll
        for (int c = 0; c < 2; ++c)
            vf[dn][c] = *(const short8*)(&Vt[(size_t)(h * DKH + dn * 16 + l16) * SEQ + k0 + c * 32 + m * 8]);
}

__device__ __forceinline__ void attn_tile(int k0, bool masked, int q0, int l16, int m,
                                          int srcA, int srcB, bool hi,
                                          const short8 (&kf)[4][2], const short8 (&vf)[4][2],
                                          const short8 (&qf)[2][2],
                                          f32x4 (&oacc)[2][4], float (&mr)[2], float (&lr)[2]) {
    f32x4 zero = {0.f, 0.f, 0.f, 0.f};
    f32x4 s[2][4];
    #pragma unroll
    for (int g = 0; g < 2; ++g)
        #pragma unroll
        for (int n = 0; n < 4; ++n) {
            f32x4 a = zero;
            a = __builtin_amdgcn_mfma_f32_16x16x32_bf16(kf[n][0], qf[g][0], a, 0, 0, 0);
            a = __builtin_amdgcn_mfma_f32_16x16x32_bf16(kf[n][1], qf[g][1], a, 0, 0, 0);
            s[g][n] = a;
        }

    unsigned pk01[2][4], pk23[2][4];
    #pragma unroll
    for (int g = 0; g < 2; ++g) {
        const int q = q0 + g * 16 + l16;
        float tm = -1e30f;
        #pragma unroll
        for (int n = 0; n < 4; ++n)
            #pragma unroll
            for (int r = 0; r < 4; ++r) {
                float v = s[g][n][r];
                if (masked && (k0 + n * 16 + m * 4 + r) > q) v = -1e30f;
                s[g][n][r] = v;
                tm = fmaxf(tm, v);
            }
        tm = fmaxf(tm, __shfl_xor(tm, 16, 64));
        tm = fmaxf(tm, __shfl_xor(tm, 32, 64));
        float mnew = fmaxf(mr[g], tm);
        float alpha = __expf(mr[g] - mnew);
        mr[g] = mnew;
        float rs = 0.f;
        #pragma unroll
        for (int n = 0; n < 4; ++n) {
            float p0 = __expf(s[g][n][0] - mnew);
            float p1 = __expf(s[g][n][1] - mnew);
            float p2 = __expf(s[g][n][2] - mnew);
            float p3 = __expf(s[g][n][3] - mnew);
            rs += (p0 + p1) + (p2 + p3);
            pk01[g][n] = pack_bf2(p0, p1);
            pk23[g][n] = pack_bf2(p2, p3);
        }
        rs += __shfl_xor(rs, 16, 64);
        rs += __shfl_xor(rs, 32, 64);
        lr[g] = lr[g] * alpha + rs;
        #pragma unroll
        for (int dn = 0; dn < 4; ++dn)
            #pragma unroll
            for (int r = 0; r < 4; ++r) oacc[g][dn][r] *= alpha;
    }

    #pragma unroll
    for (int g = 0; g < 2; ++g) {
        union { short8 s8; unsigned u[4]; } bfr[2];
        #pragma unroll
        for (int cb = 0; cb < 2; ++cb) {
            unsigned w0a = __shfl((int)pk01[g][2 * cb], srcA, 64);
            unsigned w0b = __shfl((int)pk01[g][2 * cb + 1], srcA, 64);
            unsigned w1a = __shfl((int)pk23[g][2 * cb], srcA, 64);
            unsigned w1b = __shfl((int)pk23[g][2 * cb + 1], srcA, 64);
            unsigned w2a = __shfl((int)pk01[g][2 * cb], srcB, 64);
            unsigned w2b = __shfl((int)pk01[g][2 * cb + 1], srcB, 64);
            unsigned w3a = __shfl((int)pk23[g][2 * cb], srcB, 64);
            unsigned w3b = __shfl((int)pk23[g][2 * cb + 1], srcB, 64);
            bfr[cb].u[0] = hi ? w0b : w0a;
            bfr[cb].u[1] = hi ? w1b : w1a;
            bfr[cb].u[2] = hi ? w2b : w2a;
            bfr[cb].u[3] = hi ? w3b : w3a;
        }
        #pragma unroll
        for (int dn = 0; dn < 4; ++dn) {
            oacc[g][dn] = __builtin_amdgcn_mfma_f32_16x16x32_bf16(vf[dn][0], bfr[0].s8, oacc[g][dn], 0, 0, 0);
            oacc[g][dn] = __builtin_amdgcn_mfma_f32_16x16x32_bf16(vf[dn][1], bfr[1].s8, oacc[g][dn], 0, 0, 0);
        }
    }
}

// grid: (64 * NSPLIT, NHEAD), block 64.
// Partials: Opart bf16 [h][2048][NSPLIT][64] (unnormalized numerator, transposed per-lane as in ctx),
//           Mpart/Lpart f32 [h][2048][NSPLIT].
__global__ __launch_bounds__(64) void attn_kernel(const bf16* __restrict__ Q,
                                                  const bf16* __restrict__ K,
                                                  const bf16* __restrict__ Vt,
                                                  bf16* __restrict__ Opart,
                                                  float* __restrict__ Mpart,
                                                  float* __restrict__ Lpart) {
    const int bx = blockIdx.x;
    const int qt = 63 - (bx >> 1);        // longest tiles launch first
    const int sp = bx & 1;
    const int h = blockIdx.y;
    const int lane = threadIdx.x;
    const int l16 = lane & 15, m = lane >> 4;
    const int q0 = qt * 32;

    short8 qf[2][2];
    #pragma unroll
    for (int g = 0; g < 2; ++g)
        #pragma unroll
        for (int c = 0; c < 2; ++c)
            qf[g][c] = *(const short8*)(&Q[(size_t)(q0 + g * 16 + l16) * DMODEL + h * DKH + c * 32 + m * 8]);

    f32x4 oacc[2][4];
    #pragma unroll
    for (int g = 0; g < 2; ++g)
        #pragma unroll
        for (int dn = 0; dn < 4; ++dn) oacc[g][dn] = (f32x4){0.f, 0.f, 0.f, 0.f};
    float mr[2] = {-1e30f, -1e30f};
    float lr[2] = {0.f, 0.f};

    const int nt = (qt >> 1) + 1;
    const int lo = (nt * sp) / NSPLIT;
    const int hi_t = (nt * (sp + 1)) / NSPLIT;

    const int srcA = l16 + ((m & 1) << 5);
    const int srcB = srcA + 16;
    const bool hi = (m >> 1) != 0;

    short8 kfA[4][2], vfA[4][2], kfB[4][2], vfB[4][2];

    if (lo < hi_t) {
        load_kv(lo * 64, h, l16, m, K, Vt, kfA, vfA);
        int t = lo;
        for (;;) {
            if (t + 1 < hi_t) load_kv((t + 1) * 64, h, l16, m, K, Vt, kfB, vfB);
            attn_tile(t * 64, t == nt - 1, q0, l16, m, srcA, srcB, hi, kfA, vfA, qf, oacc, mr, lr);
            ++t; if (t >= hi_t) break;
            if (t + 1 < hi_t) load_kv((t + 1) * 64, h, l16, m, K, Vt, kfA, vfA);
            attn_tile(t * 64, t == nt - 1, q0, l16, m, srcA, srcB, hi, kfB, vfB, qf, oacc, mr, lr);
            ++t; if (t >= hi_t) break;
        }
    }

    // write partials (zeros/-1e30 naturally if this split was empty)
    #pragma unroll
    for (int g = 0; g < 2; ++g) {
        const int q = q0 + g * 16 + l16;
        bf16* base = Opart + ((size_t)(h * SEQ + q) * NSPLIT + sp) * 64 + m * 4;
        #pragma unroll
        for (int dn = 0; dn < 4; ++dn) {
            unsigned a = pack_bf2(oacc[g][dn][0], oacc[g][dn][1]);
            unsigned b = pack_bf2(oacc[g][dn][2], oacc[g][dn][3]);
            *(unsigned*)(base + dn * 16) = a;
            *(unsigned*)(base + dn * 16 + 2) = b;
        }
        if (m == 0) {
            Mpart[(size_t)(h * SEQ + q) * NSPLIT + sp] = mr[g];
            Lpart[(size_t)(h * SEQ + q) * NSPLIT + sp] = lr[g];
        }
    }
}

// ---------------- combine partials -> ctx ----------------
__global__ __launch_bounds__(256) void attn_combine(const bf16* __restrict__ Opart,
                                                    const float* __restrict__ Mpart,
                                                    const float* __restrict__ Lpart,
                                                    bf16* __restrict__ ctx) {
    const int flat = blockIdx.x * 256 + threadIdx.x;   // h*32768 + q*16 + d4
    const int d4 = flat & 15;
    const int q = (flat >> 4) & 2047;
    const int h = flat >> 15;
    const size_t pbase = (size_t)(h * SEQ + q) * NSPLIT;
    const float m0 = Mpart[pbase + 0], m1 = Mpart[pbase + 1];
    const float l0 = Lpart[pbase + 0], l1 = Lpart[pbase + 1];
    const float mm = fmaxf(m0, m1);
    const float w0 = __expf(m0 - mm), w1 = __expf(m1 - mm);
    const float inv = 1.f / (l0 * w0 + l1 * w1);
    const ushort4 o0 = *(const ushort4*)(&Opart[(pbase + 0) * 64 + d4 * 4]);
    const ushort4 o1 = *(const ushort4*)(&Opart[(pbase + 1) * 64 + d4 * 4]);
    ushort4 o;
    {
        unsigned v;
        v = (unsigned)o0.x << 16; float a = *(float*)&v;
        v = (unsigned)o1.x << 16; float b = *(float*)&v;
        o.x = f2bf_bits((a * w0 + b * w1) * inv);
        v = (unsigned)o0.y << 16; a = *(float*)&v;
        v = (unsigned)o1.y << 16; b = *(float*)&v;
        o.y = f2bf_bits((a * w0 + b * w1) * inv);
        v = (unsigned)o0.z << 16; a = *(float*)&v;
        v = (unsigned)o1.z << 16; b = *(float*)&v;
        o.z = f2bf_bits((a * w0 + b * w1) * inv);
        v = (unsigned)o0.w << 16; a = *(float*)&v;
        v = (unsigned)o1.w << 16; b = *(float*)&v;
        o.w = f2bf_bits((a * w0 + b * w1) * inv);
    }
    *(ushort4*)(&ctx[(size_t)q * DMODEL + h * DKH + d4 * 4]) = o;
}

// ---------------- row LayerNorm ----------------
__global__ __launch_bounds__(256) void ln_kernel(const float* __restrict__ y,
                                                 const float* __restrict__ gamma,
                                                 const float* __restrict__ beta,
                                                 float* __restrict__ out) {
    const int row = blockIdx.x;
    const int col = threadIdx.x * 4;
    float4 v = *(const float4*)(y + row * DMODEL + col);
    float s = v.x + v.y + v.z + v.w;
    float q = v.x * v.x + v.y * v.y + v.z * v.z + v.w * v.w;
    for (int off = 1; off < 64; off <<= 1) {
        s += __shfl_xor(s, off, 64);
        q += __shfl_xor(q, off, 64);
    }
    __shared__ float ss[4], sq[4];
    int wid = threadIdx.x >> 6;
    if ((threadIdx.x & 63) == 0) { ss[wid] = s; sq[wid] = q; }
    __syncthreads();
    s = ss[0] + ss[1] + ss[2] + ss[3];
    q = sq[0] + sq[1] + sq[2] + sq[3];
    float mu = s * (1.f / DMODEL);
    float var = q * (1.f / DMODEL) - mu * mu;
    float rstd = rsqrtf(var + 1e-5f);
    float4 g = *(const float4*)(gamma + col);
    float4 b = *(const float4*)(beta + col);
    float4 o;
    o.x = (v.x - mu) * rstd * g.x + b.x;
    o.y = (v.y - mu) * rstd * g.y + b.y;
    o.z = (v.z - mu) * rstd * g.z + b.z;
    o.w = (v.w - mu) * rstd * g.w + b.w;
    *(float4*)(out + row * DMODEL + col) = o;
}

extern "C" void kernel_launch(void* const* d_in, const int* in_sizes, int n_in,
                              void* d_out, int out_size, void* d_ws, size_t ws_size,
                              hipStream_t stream) {
    const float* x     = (const float*)d_in[0];
    const float* Wq    = (const float*)d_in[1];
    const float* bq    = (const float*)d_in[2];
    const float* Wk    = (const float*)d_in[3];
    const float* bk    = (const float*)d_in[4];
    const float* Wv    = (const float*)d_in[5];
    const float* bv    = (const float*)d_in[6];
    const float* Wo    = (const float*)d_in[7];
    const float* bo    = (const float*)d_in[8];
    const float* gamma = (const float*)d_in[9];
    const float* beta  = (const float*)d_in[10];
    float* out = (float*)d_out;

    char* w = (char*)d_ws;
    bf16* xb   = (bf16*)w;  w += (size_t)SEQ * DMODEL * 2;        // dead after QKV gemm
    bf16* Wqt  = (bf16*)w;  w += (size_t)DMODEL * DMODEL * 2;     // Wqt,Wkt,Wvt,Wot contiguous
    bf16* Wkt  = (bf16*)w;  w += (size_t)DMODEL * DMODEL * 2;
    bf16* Wvt  = (bf16*)w;  w += (size_t)DMODEL * DMODEL * 2;
    bf16* Wot  = (bf16*)w;  w += (size_t)DMODEL * DMODEL * 2;
    bf16* Qb   = (bf16*)w;  w += (size_t)SEQ * DMODEL * 2;
    bf16* Kb   = (bf16*)w;  w += (size_t)SEQ * DMODEL * 2;
    bf16* Vtb  = (bf16*)w;  w += (size_t)DMODEL * SEQ * 2;
    bf16* ctxb = (bf16*)w;  w += (size_t)SEQ * DMODEL * 2;
    float* yb  = (float*)w; w += (size_t)SEQ * DMODEL * 4;        // written after combine

    // overlays: attention partials live in buffers dead during attn/combine
    bf16* Opart  = (bf16*)yb;                                     // 8 MiB, exactly yb's size
    float* Mpart = (float*)xb;                                    // in xb (dead post-QKV)
    float* Lpart = Mpart + (size_t)NHEAD * SEQ * NSPLIT;

    // 1. cast x
    cast_x_kernel<<<SEQ * DMODEL / (256 * 4), 256, 0, stream>>>(x, xb);

    // 2. transpose+cast all weights (one launch)
    dim3 tgrid(DMODEL / 32, DMODEL / 32, 4), tblk(32, 8);
    transpose_cast_w4<<<tgrid, tblk, 0, stream>>>(Wq, Wk, Wv, Wo, Wqt);

    // 3. fused QKV projection (Q pre-scaled by 1/8)
    dim3 qkvgrid(3 * DMODEL / 128, SEQ / 128);
    gemm128<1><<<qkvgrid, 256, 0, stream>>>(xb, Wqt, bq, bk, bv, Qb, Kb, Vtb, nullptr, nullptr);

    // 4. attention (key-split partials)
    dim3 agrid(64 * NSPLIT, NHEAD);
    attn_kernel<<<agrid, 64, 0, stream>>>(Qb, Kb, Vtb, Opart, Mpart, Lpart);

    // 4.5 combine
    attn_combine<<<NHEAD * SEQ * 16 / 256, 256, 0, stream>>>(Opart, Mpart, Lpart, ctxb);

    // 5. output projection + residual
    dim3 ogrid(DMODEL / 128, SEQ / 128);
    gemm128<0><<<ogrid, 256, 0, stream>>>(ctxb, Wot, bo, nullptr, nullptr, nullptr, nullptr, nullptr, x, yb);

    // 6. LayerNorm
    ln_kernel<<<SEQ, 256, 0, stream>>>(yb, gamma, beta, out);
}

// Round 5
// 116.013 us; speedup vs baseline: 1.6602x; 1.1568x over previous
//
#include <hip/hip_runtime.h>
#include <hip/hip_bf16.h>

#define SEQ 2048
#define DMODEL 1024
#define NHEAD 16
#define DKH 64
#define NSPLIT 2

typedef __hip_bfloat16 bf16;
typedef __attribute__((ext_vector_type(8))) short short8;
typedef __attribute__((ext_vector_type(4))) float f32x4;

__device__ __forceinline__ unsigned short f2bf_bits(float f) {
    bf16 h = __float2bfloat16(f);
    return *reinterpret_cast<unsigned short*>(&h);
}

__device__ __forceinline__ unsigned pack_bf2(float a, float b) {
    return (unsigned)f2bf_bits(a) | ((unsigned)f2bf_bits(b) << 16);
}

// ---------------- cast x (fp32 -> bf16) ----------------
__global__ __launch_bounds__(256) void cast_x_kernel(const float* __restrict__ x,
                                                     bf16* __restrict__ xb) {
    int i = (blockIdx.x * 256 + threadIdx.x) * 4;
    float4 v = *(const float4*)(x + i);
    ushort4 o;
    o.x = f2bf_bits(v.x); o.y = f2bf_bits(v.y);
    o.z = f2bf_bits(v.z); o.w = f2bf_bits(v.w);
    *(ushort4*)(xb + i) = o;
}

// ---------------- batched transpose+cast: 4 weights in one launch ----------------
__global__ __launch_bounds__(256) void transpose_cast_w4(const float* __restrict__ W0,
                                                         const float* __restrict__ W1,
                                                         const float* __restrict__ W2,
                                                         const float* __restrict__ W3,
                                                         bf16* __restrict__ Wt) {
    const float* W = (blockIdx.z == 0) ? W0 : (blockIdx.z == 1) ? W1 : (blockIdx.z == 2) ? W2 : W3;
    bf16* out = Wt + (size_t)blockIdx.z * DMODEL * DMODEL;
    __shared__ float tile[32][33];
    int bx = blockIdx.x * 32;
    int by = blockIdx.y * 32;
    int tx = threadIdx.x;
    int ty = threadIdx.y;
    for (int i = 0; i < 32; i += 8)
        tile[ty + i][tx] = W[(by + ty + i) * DMODEL + bx + tx];
    __syncthreads();
    for (int i = 0; i < 32; i += 8)
        out[(bx + ty + i) * DMODEL + by + tx] = __float2bfloat16(tile[tx][ty + i]);
}

// ---------------- 128x128 GEMM, BK=64, global_load_lds staging (m97 structure) ----------------
template <int FUSED>
__global__ __launch_bounds__(256) void gemm128(const bf16* __restrict__ A,
                                               const bf16* __restrict__ Bt,
                                               const float* __restrict__ b0,
                                               const float* __restrict__ b1,
                                               const float* __restrict__ b2,
                                               bf16* __restrict__ Qb,
                                               bf16* __restrict__ Kb,
                                               bf16* __restrict__ Vtb,
                                               const float* __restrict__ resid,
                                               float* __restrict__ yout) {
    const int m0 = blockIdx.y * 128;
    const int n0 = blockIdx.x * 128;
    __shared__ __align__(16) bf16 As[128 * 64];
    __shared__ __align__(16) bf16 Bs[128 * 64];
    const int tid = threadIdx.x, lane = tid & 63, wid = tid >> 6;
    const int l16 = lane & 15, lhi = lane >> 4;
    const int wr = wid >> 1, wc = wid & 1;

    f32x4 acc[4][4];
    for (int i = 0; i < 4; ++i)
        for (int j = 0; j < 4; ++j) acc[i][j] = (f32x4){0.f, 0.f, 0.f, 0.f};

    for (int kt = 0; kt < DMODEL; kt += 64) {
        __syncthreads();
        #pragma unroll
        for (int j = 0; j < 4; ++j) {
            const int cb = (j * 4 + wid) * 64;
            const int chunk = cb + lane;
            const int row = chunk >> 3, c16 = chunk & 7;
            const bf16* gA = A + (size_t)(m0 + row) * DMODEL + kt + c16 * 8;
            const bf16* gB = Bt + (size_t)(n0 + row) * DMODEL + kt + c16 * 8;
            __builtin_amdgcn_global_load_lds((const __attribute__((address_space(1))) void*)gA,
                                             (__attribute__((address_space(3))) void*)(As + cb * 8),
                                             16, 0, 0);
            __builtin_amdgcn_global_load_lds((const __attribute__((address_space(1))) void*)gB,
                                             (__attribute__((address_space(3))) void*)(Bs + cb * 8),
                                             16, 0, 0);
        }
        __syncthreads();
        #pragma unroll
        for (int c = 0; c < 2; ++c) {
            short8 af[4], bfm[4];
            #pragma unroll
            for (int mi = 0; mi < 4; ++mi)
                af[mi] = *(const short8*)(&As[(wr * 64 + mi * 16 + l16) * 64 + c * 32 + lhi * 8]);
            #pragma unroll
            for (int ni = 0; ni < 4; ++ni)
                bfm[ni] = *(const short8*)(&Bs[(wc * 64 + ni * 16 + l16) * 64 + c * 32 + lhi * 8]);
            #pragma unroll
            for (int mi = 0; mi < 4; ++mi)
                #pragma unroll
                for (int ni = 0; ni < 4; ++ni)
                    acc[mi][ni] = __builtin_amdgcn_mfma_f32_16x16x32_bf16(af[mi], bfm[ni], acc[mi][ni], 0, 0, 0);
        }
    }

    if (FUSED) {
        const int reg = n0 >> 10;
        const float* bias = (reg == 0) ? b0 : (reg == 1) ? b1 : b2;
        const int nb = n0 & 1023;
        #pragma unroll
        for (int mi = 0; mi < 4; ++mi)
            #pragma unroll
            for (int ni = 0; ni < 4; ++ni) {
                const int gm = m0 + wr * 64 + mi * 16 + lhi * 4;
                const int gn = nb + wc * 64 + ni * 16 + l16;
                const float bv = bias[gn];
                if (reg == 0) {
                    for (int r = 0; r < 4; ++r)
                        Qb[(size_t)(gm + r) * DMODEL + gn] = __float2bfloat16((acc[mi][ni][r] + bv) * 0.125f);
                } else if (reg == 1) {
                    for (int r = 0; r < 4; ++r)
                        Kb[(size_t)(gm + r) * DMODEL + gn] = __float2bfloat16(acc[mi][ni][r] + bv);
                } else {
                    ushort4 p;
                    p.x = f2bf_bits(acc[mi][ni][0] + bv);
                    p.y = f2bf_bits(acc[mi][ni][1] + bv);
                    p.z = f2bf_bits(acc[mi][ni][2] + bv);
                    p.w = f2bf_bits(acc[mi][ni][3] + bv);
                    *(ushort4*)(&Vtb[(size_t)gn * SEQ + gm]) = p;
                }
            }
    } else {
        #pragma unroll
        for (int mi = 0; mi < 4; ++mi)
            #pragma unroll
            for (int ni = 0; ni < 4; ++ni) {
                const int gm = m0 + wr * 64 + mi * 16 + lhi * 4;
                const int gn = n0 + wc * 64 + ni * 16 + l16;
                const float bv = b0[gn];
                for (int r = 0; r < 4; ++r)
                    yout[(size_t)(gm + r) * DMODEL + gn] =
                        acc[mi][ni][r] + bv + resid[(size_t)(gm + r) * DMODEL + gn];
            }
    }
}

// ---------------- attention: 4-wave blocks, LDS-staged K/V (swizzled), dbuf prefetch ----------------
// Block = 128 queries (4 waves x 32). K-tile [64 keys][64 d] and Vt-tile [64 d][64 keys]
// staged in LDS via global_load_lds with XOR-swizzle (byte ^= (row&7)<<4), applied on the
// GLOBAL source (involution within each 128B row) + on the ds_read address.
// K-split NSPLIT=2 partials -> combine. Swapped QK^T softmax as in prior rounds.
__global__ __launch_bounds__(256) void attn_kernel(const bf16* __restrict__ Q,
                                                   const bf16* __restrict__ K,
                                                   const bf16* __restrict__ Vt,
                                                   bf16* __restrict__ Opart,
                                                   float* __restrict__ Mpart,
                                                   float* __restrict__ Lpart) {
    const int s = blockIdx.x;             // 0..31
    const int h = blockIdx.y;
    const int p = s >> 1, par = s & 1;
    int qb = par ? 15 - p : p;            // pair (qb, 15-qb) on adjacent slots
    if ((h >> 3) & 1) qb = 15 - qb;       // flip for far heads (CU pairing balance)
    const int sp = par;

    const int tid = threadIdx.x;
    const int lane = tid & 63, w = tid >> 6;
    const int l16 = lane & 15, m = lane >> 4;
    const int q0w = qb * 128 + w * 32;    // this wave's first query

    __shared__ __align__(16) bf16 Ks[2][64 * 64];
    __shared__ __align__(16) bf16 Vs[2][64 * 64];

    // Q fragments (B-operand)
    short8 qf[2][2];
    #pragma unroll
    for (int g = 0; g < 2; ++g)
        #pragma unroll
        for (int c = 0; c < 2; ++c)
            qf[g][c] = *(const short8*)(&Q[(size_t)(q0w + g * 16 + l16) * DMODEL + h * DKH + c * 32 + m * 8]);

    f32x4 oacc[2][4];
    #pragma unroll
    for (int g = 0; g < 2; ++g)
        #pragma unroll
        for (int dn = 0; dn < 4; ++dn) oacc[g][dn] = (f32x4){0.f, 0.f, 0.f, 0.f};
    float mr[2] = {-1e30f, -1e30f};
    float lr[2] = {0.f, 0.f};

    const int lo = sp * (qb + 1);
    const int hi_t = lo + (qb + 1);

    const int srcA = l16 + ((m & 1) << 5);
    const int srcB = srcA + 16;
    const bool hilane = (m >> 1) != 0;

    // staging: thread tid fills 16B at linear LDS offset (j*4096 + tid*16) bytes;
    // global source column is pre-swizzled so that swizzled ds_reads see logical data.
    const int r0 = tid >> 3;
    const int cbyte = (tid & 7) * 16;
    auto stage = [&](int t, int buf) {
        #pragma unroll
        for (int j = 0; j < 2; ++j) {
            const int r = j * 32 + r0;
            const int sc = cbyte ^ ((r & 7) << 4);   // swizzled source byte offset in row
            const bf16* gk = K + (size_t)(t * 64 + r) * DMODEL + h * DKH + (sc >> 1);
            const bf16* gv = Vt + (size_t)(h * DKH + r) * SEQ + t * 64 + (sc >> 1);
            __builtin_amdgcn_global_load_lds((const __attribute__((address_space(1))) void*)gk,
                                             (__attribute__((address_space(3))) void*)(&Ks[buf][j * 2048 + tid * 8]),
                                             16, 0, 0);
            __builtin_amdgcn_global_load_lds((const __attribute__((address_space(1))) void*)gv,
                                             (__attribute__((address_space(3))) void*)(&Vs[buf][j * 2048 + tid * 8]),
                                             16, 0, 0);
        }
    };

    stage(lo, 0);
    __syncthreads();

    const int rsw = (l16 & 7) << 3;   // element-offset XOR for swizzled ds_read

    for (int t = lo; t < hi_t; ++t) {
        const int cur = (t - lo) & 1;
        if (t + 1 < hi_t) stage(t + 1, cur ^ 1);
        const int k0 = t * 64;

        if (k0 <= q0w + 31) {          // wave has at least one unmasked row in this tile
            // mask needed iff any key in tile can exceed the wave's MINIMUM query
            const bool masked = (k0 + 63 > q0w);

            short8 kf[4][2], vf[4][2];
            #pragma unroll
            for (int n = 0; n < 4; ++n)
                #pragma unroll
                for (int c = 0; c < 2; ++c)
                    kf[n][c] = *(const short8*)(&Ks[cur][(n * 16 + l16) * 64 + ((c * 32 + m * 8) ^ rsw)]);
            #pragma unroll
            for (int dn = 0; dn < 4; ++dn)
                #pragma unroll
                for (int c = 0; c < 2; ++c)
                    vf[dn][c] = *(const short8*)(&Vs[cur][(dn * 16 + l16) * 64 + ((c * 32 + m * 8) ^ rsw)]);

            // S^T = K Q^T
            f32x4 sv[2][4];
            #pragma unroll
            for (int g = 0; g < 2; ++g)
                #pragma unroll
                for (int n = 0; n < 4; ++n) {
                    f32x4 a = (f32x4){0.f, 0.f, 0.f, 0.f};
                    a = __builtin_amdgcn_mfma_f32_16x16x32_bf16(kf[n][0], qf[g][0], a, 0, 0, 0);
                    a = __builtin_amdgcn_mfma_f32_16x16x32_bf16(kf[n][1], qf[g][1], a, 0, 0, 0);
                    sv[g][n] = a;
                }

            unsigned pk01[2][4], pk23[2][4];
            #pragma unroll
            for (int g = 0; g < 2; ++g) {
                const int q = q0w + g * 16 + l16;
                float tm = -1e30f;
                #pragma unroll
                for (int n = 0; n < 4; ++n)
                    #pragma unroll
                    for (int r = 0; r < 4; ++r) {
                        float v = sv[g][n][r];
                        if (masked && (k0 + n * 16 + m * 4 + r) > q) v = -1e30f;
                        sv[g][n][r] = v;
                        tm = fmaxf(tm, v);
                    }
                tm = fmaxf(tm, __shfl_xor(tm, 16, 64));
                tm = fmaxf(tm, __shfl_xor(tm, 32, 64));
                float mnew = fmaxf(mr[g], tm);
                float alpha = __expf(mr[g] - mnew);
                mr[g] = mnew;
                float rs = 0.f;
                #pragma unroll
                for (int n = 0; n < 4; ++n) {
                    float p0 = __expf(sv[g][n][0] - mnew);
                    float p1 = __expf(sv[g][n][1] - mnew);
                    float p2 = __expf(sv[g][n][2] - mnew);
                    float p3 = __expf(sv[g][n][3] - mnew);
                    rs += (p0 + p1) + (p2 + p3);
                    pk01[g][n] = pack_bf2(p0, p1);
                    pk23[g][n] = pack_bf2(p2, p3);
                }
                rs += __shfl_xor(rs, 16, 64);
                rs += __shfl_xor(rs, 32, 64);
                lr[g] = lr[g] * alpha + rs;
                #pragma unroll
                for (int dn = 0; dn < 4; ++dn)
                    #pragma unroll
                    for (int r = 0; r < 4; ++r) oacc[g][dn][r] *= alpha;
            }

            // P^T B-frags by shuffle, then PV
            #pragma unroll
            for (int g = 0; g < 2; ++g) {
                union { short8 s8; unsigned u[4]; } bfr[2];
                #pragma unroll
                for (int cb = 0; cb < 2; ++cb) {
                    unsigned w0a = __shfl((int)pk01[g][2 * cb], srcA, 64);
                    unsigned w0b = __shfl((int)pk01[g][2 * cb + 1], srcA, 64);
                    unsigned w1a = __shfl((int)pk23[g][2 * cb], srcA, 64);
                    unsigned w1b = __shfl((int)pk23[g][2 * cb + 1], srcA, 64);
                    unsigned w2a = __shfl((int)pk01[g][2 * cb], srcB, 64);
                    unsigned w2b = __shfl((int)pk01[g][2 * cb + 1], srcB, 64);
                    unsigned w3a = __shfl((int)pk23[g][2 * cb], srcB, 64);
                    unsigned w3b = __shfl((int)pk23[g][2 * cb + 1], srcB, 64);
                    bfr[cb].u[0] = hilane ? w0b : w0a;
                    bfr[cb].u[1] = hilane ? w1b : w1a;
                    bfr[cb].u[2] = hilane ? w2b : w2a;
                    bfr[cb].u[3] = hilane ? w3b : w3a;
                }
                #pragma unroll
                for (int dn = 0; dn < 4; ++dn) {
                    oacc[g][dn] = __builtin_amdgcn_mfma_f32_16x16x32_bf16(vf[dn][0], bfr[0].s8, oacc[g][dn], 0, 0, 0);
                    oacc[g][dn] = __builtin_amdgcn_mfma_f32_16x16x32_bf16(vf[dn][1], bfr[1].s8, oacc[g][dn], 0, 0, 0);
                }
            }
        }
        __syncthreads();
    }

    // write partials
    #pragma unroll
    for (int g = 0; g < 2; ++g) {
        const int q = q0w + g * 16 + l16;
        bf16* base = Opart + ((size_t)(h * SEQ + q) * NSPLIT + sp) * 64 + m * 4;
        #pragma unroll
        for (int dn = 0; dn < 4; ++dn) {
            unsigned a = pack_bf2(oacc[g][dn][0], oacc[g][dn][1]);
            unsigned b = pack_bf2(oacc[g][dn][2], oacc[g][dn][3]);
            *(unsigned*)(base + dn * 16) = a;
            *(unsigned*)(base + dn * 16 + 2) = b;
        }
        if (m == 0) {
            Mpart[(size_t)(h * SEQ + q) * NSPLIT + sp] = mr[g];
            Lpart[(size_t)(h * SEQ + q) * NSPLIT + sp] = lr[g];
        }
    }
}

// ---------------- combine partials -> ctx ----------------
__global__ __launch_bounds__(256) void attn_combine(const bf16* __restrict__ Opart,
                                                    const float* __restrict__ Mpart,
                                                    const float* __restrict__ Lpart,
                                                    bf16* __restrict__ ctx) {
    const int flat = blockIdx.x * 256 + threadIdx.x;
    const int d4 = flat & 15;
    const int q = (flat >> 4) & 2047;
    const int h = flat >> 15;
    const size_t pbase = (size_t)(h * SEQ + q) * NSPLIT;
    const float m0 = Mpart[pbase + 0], m1 = Mpart[pbase + 1];
    const float l0 = Lpart[pbase + 0], l1 = Lpart[pbase + 1];
    const float mm = fmaxf(m0, m1);
    const float w0 = __expf(m0 - mm), w1 = __expf(m1 - mm);
    const float inv = 1.f / (l0 * w0 + l1 * w1);
    const ushort4 o0 = *(const ushort4*)(&Opart[(pbase + 0) * 64 + d4 * 4]);
    const ushort4 o1 = *(const ushort4*)(&Opart[(pbase + 1) * 64 + d4 * 4]);
    ushort4 o;
    {
        unsigned v;
        v = (unsigned)o0.x << 16; float a = *(float*)&v;
        v = (unsigned)o1.x << 16; float b = *(float*)&v;
        o.x = f2bf_bits((a * w0 + b * w1) * inv);
        v = (unsigned)o0.y << 16; a = *(float*)&v;
        v = (unsigned)o1.y << 16; b = *(float*)&v;
        o.y = f2bf_bits((a * w0 + b * w1) * inv);
        v = (unsigned)o0.z << 16; a = *(float*)&v;
        v = (unsigned)o1.z << 16; b = *(float*)&v;
        o.z = f2bf_bits((a * w0 + b * w1) * inv);
        v = (unsigned)o0.w << 16; a = *(float*)&v;
        v = (unsigned)o1.w << 16; b = *(float*)&v;
        o.w = f2bf_bits((a * w0 + b * w1) * inv);
    }
    *(ushort4*)(&ctx[(size_t)q * DMODEL + h * DKH + d4 * 4]) = o;
}

// ---------------- row LayerNorm ----------------
__global__ __launch_bounds__(256) void ln_kernel(const float* __restrict__ y,
                                                 const float* __restrict__ gamma,
                                                 const float* __restrict__ beta,
                                                 float* __restrict__ out) {
    const int row = blockIdx.x;
    const int col = threadIdx.x * 4;
    float4 v = *(const float4*)(y + row * DMODEL + col);
    float s = v.x + v.y + v.z + v.w;
    float q = v.x * v.x + v.y * v.y + v.z * v.z + v.w * v.w;
    for (int off = 1; off < 64; off <<= 1) {
        s += __shfl_xor(s, off, 64);
        q += __shfl_xor(q, off, 64);
    }
    __shared__ float ss[4], sq[4];
    int wid = threadIdx.x >> 6;
    if ((threadIdx.x & 63) == 0) { ss[wid] = s; sq[wid] = q; }
    __syncthreads();
    s = ss[0] + ss[1] + ss[2] + ss[3];
    q = sq[0] + sq[1] + sq[2] + sq[3];
    float mu = s * (1.f / DMODEL);
    float var = q * (1.f / DMODEL) - mu * mu;
    float rstd = rsqrtf(var + 1e-5f);
    float4 g = *(const float4*)(gamma + col);
    float4 b = *(const float4*)(beta + col);
    float4 o;
    o.x = (v.x - mu) * rstd * g.x + b.x;
    o.y = (v.y - mu) * rstd * g.y + b.y;
    o.z = (v.z - mu) * rstd * g.z + b.z;
    o.w = (v.w - mu) * rstd * g.w + b.w;
    *(float4*)(out + row * DMODEL + col) = o;
}

extern "C" void kernel_launch(void* const* d_in, const int* in_sizes, int n_in,
                              void* d_out, int out_size, void* d_ws, size_t ws_size,
                              hipStream_t stream) {
    const float* x     = (const float*)d_in[0];
    const float* Wq    = (const float*)d_in[1];
    const float* bq    = (const float*)d_in[2];
    const float* Wk    = (const float*)d_in[3];
    const float* bk    = (const float*)d_in[4];
    const float* Wv    = (const float*)d_in[5];
    const float* bv    = (const float*)d_in[6];
    const float* Wo    = (const float*)d_in[7];
    const float* bo    = (const float*)d_in[8];
    const float* gamma = (const float*)d_in[9];
    const float* beta  = (const float*)d_in[10];
    float* out = (float*)d_out;

    char* w = (char*)d_ws;
    bf16* xb   = (bf16*)w;  w += (size_t)SEQ * DMODEL * 2;        // dead after QKV gemm
    bf16* Wqt  = (bf16*)w;  w += (size_t)DMODEL * DMODEL * 2;
    bf16* Wkt  = (bf16*)w;  w += (size_t)DMODEL * DMODEL * 2;
    bf16* Wvt  = (bf16*)w;  w += (size_t)DMODEL * DMODEL * 2;
    bf16* Wot  = (bf16*)w;  w += (size_t)DMODEL * DMODEL * 2;
    bf16* Qb   = (bf16*)w;  w += (size_t)SEQ * DMODEL * 2;
    bf16* Kb   = (bf16*)w;  w += (size_t)SEQ * DMODEL * 2;
    bf16* Vtb  = (bf16*)w;  w += (size_t)DMODEL * SEQ * 2;
    bf16* ctxb = (bf16*)w;  w += (size_t)SEQ * DMODEL * 2;
    float* yb  = (float*)w; w += (size_t)SEQ * DMODEL * 4;

    // overlays
    bf16* Opart  = (bf16*)yb;                                     // 8 MiB
    float* Mpart = (float*)xb;
    float* Lpart = Mpart + (size_t)NHEAD * SEQ * NSPLIT;

    // 1. cast x
    cast_x_kernel<<<SEQ * DMODEL / (256 * 4), 256, 0, stream>>>(x, xb);

    // 2. transpose+cast all weights
    dim3 tgrid(DMODEL / 32, DMODEL / 32, 4), tblk(32, 8);
    transpose_cast_w4<<<tgrid, tblk, 0, stream>>>(Wq, Wk, Wv, Wo, Wqt);

    // 3. fused QKV projection (Q pre-scaled by 1/8)
    dim3 qkvgrid(3 * DMODEL / 128, SEQ / 128);
    gemm128<1><<<qkvgrid, 256, 0, stream>>>(xb, Wqt, bq, bk, bv, Qb, Kb, Vtb, nullptr, nullptr);

    // 4. attention (4-wave blocks, K-split partials)
    dim3 agrid(16 * NSPLIT, NHEAD);
    attn_kernel<<<agrid, 256, 0, stream>>>(Qb, Kb, Vtb, Opart, Mpart, Lpart);

    // 4.5 combine
    attn_combine<<<NHEAD * SEQ * 16 / 256, 256, 0, stream>>>(Opart, Mpart, Lpart, ctxb);

    // 5. output projection + residual
    dim3 ogrid(DMODEL / 128, SEQ / 128);
    gemm128<0><<<ogrid, 256, 0, stream>>>(ctxb, Wot, bo, nullptr, nullptr, nullptr, nullptr, nullptr, x, yb);

    // 6. LayerNorm
    ln_kernel<<<SEQ, 256, 0, stream>>>(yb, gamma, beta, out);
}